// Round 18
// baseline (378.414 us; speedup 1.0000x reference)
//
#include <hip/hip_runtime.h>
#include <float.h>
#include <math.h>

#define Bg   8
#define NPGc 6250
#define Hh   4
#define Dd   128
#define Nn   50000
#define Ee   400000
#define HDd  512
#define WNf  1536   // hs(512) | hd(512) | rres(512) column space
#define NCHUNK 49   // ceil(50000/1024)

typedef unsigned short ushort_t;
typedef __attribute__((ext_vector_type(8))) short bf16x8;
typedef __attribute__((ext_vector_type(4))) float f32x4;
typedef __attribute__((ext_vector_type(2))) float f32x2;
typedef __attribute__((ext_vector_type(4))) unsigned u32x4;

__device__ __forceinline__ void atomicMaxF(float* addr, float val) {
    if (val >= 0.0f) atomicMax((int*)addr, __float_as_int(val));
    else             atomicMin((unsigned int*)addr, __float_as_uint(val));
}

__device__ __forceinline__ ushort_t f2bf(float x) {
    unsigned u = __float_as_uint(x);
    unsigned r = (u + 0x7FFFu + ((u >> 16) & 1u)) >> 16;   // RNE
    return (ushort_t)r;
}

__device__ __forceinline__ f32x2 bfpair(unsigned u) {
    f32x2 r;
    r.x = __uint_as_float(u << 16);
    r.y = __uint_as_float(u & 0xFFFF0000u);
    return r;
}

// ---- fused setup: gather(bf16) | degree histograms | weight prep | pools init ----
// REQUIRES: cursor|din_i|dout_f zeroed via hipMemsetAsync before launch (fused
// degree atomics would race with in-kernel zeroing).
__global__ void setup_kernel(const int* __restrict__ ids, const float* __restrict__ emb,
                             ushort_t* __restrict__ feat_bf,
                             const int* __restrict__ src, const int* __restrict__ dst,
                             const float* __restrict__ W_src, const float* __restrict__ W_dst,
                             const float* __restrict__ W_res, const float* __restrict__ W_gc,
                             const float* __restrict__ b_src, const float* __restrict__ b_dst,
                             const float* __restrict__ b_res,
                             ushort_t* __restrict__ Wt, ushort_t* __restrict__ Wt_gc,
                             float* __restrict__ bias_f,
                             int* __restrict__ din_i, float* __restrict__ dout,
                             float* __restrict__ pools) {
    int i = blockIdx.x * blockDim.x + threadIdx.x;
    {   // gather: over N*32 float4s -> bf16
        int n = i >> 5, c = i & 31;
        int id = ids[n];
        float4 v = ((const float4*)emb)[(size_t)id * 32 + c];
        ushort4 b;
        b.x = f2bf(v.x); b.y = f2bf(v.y); b.z = f2bf(v.z); b.w = f2bf(v.w);
        ((ushort4*)feat_bf)[(size_t)n * 32 + c] = b;
    }
    if (i < Ee) {   // degree histograms (buffers pre-zeroed by memset)
        atomicAdd(&din_i[dst[i]], 1);
        atomicAdd(&dout[src[i]], 1.0f);
    }
    if (i < Bg * 3 * Dd) pools[i] = -FLT_MAX;
    if (i < WNf * 128) {
        int c = i >> 7, k = i & 127;
        float v = (c < 512) ? W_src[k * 512 + c]
                : (c < 1024) ? W_dst[k * 512 + (c - 512)]
                             : W_res[k * 512 + (c - 1024)];
        Wt[i] = f2bf(v);
    } else if (i < WNf * 128 + 128 * 128) {
        int j = i - WNf * 128;
        int c = j >> 7, k = j & 127;
        Wt_gc[j] = f2bf(W_gc[k * 128 + c]);
    }
    if (i < WNf)
        bias_f[i] = (i < 512) ? b_src[i] : (i < 1024) ? b_dst[i - 512] : b_res[i - 1024];
}

// bf16 maxpool; 64 threads, 2 cols/lane
__global__ void maxpool_bf_kernel(const ushort_t* __restrict__ x, float* __restrict__ pools, int col_off) {
    int b = blockIdx.x, chunk = blockIdx.y, lane = threadIdx.x;   // 64 threads
    int i0 = chunk * 125;
    f32x2 mx = {-FLT_MAX, -FLT_MAX};
    for (int i = 0; i < 125; ++i) {
        unsigned u = *(const unsigned*)(x + ((size_t)(b * NPGc + i0 + i)) * Dd + lane * 2);
        mx = __builtin_elementwise_max(mx, bfpair(u));
    }
    atomicMaxF(&pools[b * (3 * Dd) + col_off + lane * 2],     mx.x);
    atomicMaxF(&pools[b * (3 * Dd) + col_off + lane * 2 + 1], mx.y);
}

// ---- merged MFMA GEMM: cols 0-511 -> hs_buf, cols 512-1535 -> hdres.
// CACHED stores everywhere (R17: nt stores cut write BW 1.75->1.43 TB/s).
// XCD-locality swizzle (grid 9384 = 782 x 12, div by 8), LDS-coalesced epilogue.
#define GNT 2
#define NCS 12
__global__ __launch_bounds__(256) void mfma_gemm_kernel(
    const ushort_t* __restrict__ A, const ushort_t* __restrict__ Wt,
    const float* __restrict__ bias, ushort_t* __restrict__ Ohs,
    ushort_t* __restrict__ Odr, int n_rows)
{
    __shared__ ushort_t Cs[2][64 * 64];
    int bid = blockIdx.x;
    int lin = (bid & 7) * (gridDim.x >> 3) + (bid >> 3);
    int row0 = (lin / NCS) * 64;
    int ct0  = (lin % NCS) * GNT;
    int w = threadIdx.x >> 6, lane = threadIdx.x & 63;
    int lrow = lane & 15, kg = lane >> 4;

    bf16x8 av[4][4];
    {
        const ushort_t* ap = A + (size_t)(row0 + lrow) * 128 + kg * 8;
        #pragma unroll
        for (int fi = 0; fi < 4; ++fi)
            #pragma unroll
            for (int ks = 0; ks < 4; ++ks)
                av[fi][ks] = *(const bf16x8*)(ap + fi * 16 * 128 + ks * 32);
    }
    bf16x8 wv[GNT][4];
    float4 bv[GNT];
    {
        const ushort_t* wp = Wt + (size_t)(ct0 * 64 + w * 16 + lrow) * 128 + kg * 8;
        #pragma unroll
        for (int ct = 0; ct < GNT; ++ct) {
            #pragma unroll
            for (int ks = 0; ks < 4; ++ks)
                wv[ct][ks] = *(const bf16x8*)(wp + (size_t)ct * 8192 + ks * 32);
            bv[ct] = *(const float4*)(bias + (ct0 + ct) * 64 + w * 16 + kg * 4);
        }
    }

    #pragma unroll
    for (int ct = 0; ct < GNT; ++ct) {
        f32x4 acc[4] = {};
        #pragma unroll
        for (int ks = 0; ks < 4; ++ks)
            #pragma unroll
            for (int fi = 0; fi < 4; ++fi)
                acc[fi] = __builtin_amdgcn_mfma_f32_16x16x32_bf16(wv[ct][ks], av[fi][ks], acc[fi], 0, 0, 0);

        ushort_t* cb = Cs[ct & 1];
        int cbase = w * 32 + kg * 8;
        #pragma unroll
        for (int fi = 0; fi < 4; ++fi) {
            float o0 = acc[fi][0] + bv[ct].x;
            float o1 = acc[fi][1] + bv[ct].y;
            float o2 = acc[fi][2] + bv[ct].z;
            float o3 = acc[fi][3] + bv[ct].w;
            unsigned q0, q1;
            asm("v_cvt_pk_bf16_f32 %0, %1, %2" : "=v"(q0) : "v"(o0), "v"(o1));
            asm("v_cvt_pk_bf16_f32 %0, %1, %2" : "=v"(q1) : "v"(o2), "v"(o3));
            int r = fi * 16 + lrow;
            int cbyte = cbase ^ ((r & 7) << 4);
            uint2 q; q.x = q0; q.y = q1;
            *(uint2*)((char*)cb + r * 128 + cbyte) = q;
        }
        __syncthreads();
        {
            int t = threadIdx.x;
            const char* cbr = (const char*)cb;
            int gcol = (ct0 + ct) * 64;
            char* ob; int wn;
            if (gcol < 512) { ob = (char*)Ohs; wn = 512; }
            else            { ob = (char*)Odr; wn = 1024; gcol -= 512; }
            #pragma unroll
            for (int h = 0; h < 2; ++h) {
                int r  = (h * 256 + t) >> 3;
                int ch = t & 7;
                int cbyte = (ch * 16) ^ ((r & 7) << 4);
                u32x4 v = *(const u32x4*)(cbr + r * 128 + cbyte);
                int grow = row0 + r;
                if (grow < n_rows)
                    *(u32x4*)(ob + ((size_t)grow * wn + gcol) * 2 + ch * 16) = v;
            }
        }
    }
}

// ---- GraphConv GEMM fused with maxpool2 ----
__global__ __launch_bounds__(256) void mfma_gc_pool_kernel(
    const ushort_t* __restrict__ A, const ushort_t* __restrict__ Wt,
    const float* __restrict__ bias, float* __restrict__ pools)
{
    int g = blockIdx.x / 98, lb = blockIdx.x % 98;
    int row0 = g * NPGc + lb * 64;
    int w = threadIdx.x >> 6, lane = threadIdx.x & 63;
    int lrow = lane & 15, kg = lane >> 4;

    bf16x8 av[4][4];
    {
        const ushort_t* ap = A + (size_t)(row0 + lrow) * 128 + kg * 8;
        #pragma unroll
        for (int fi = 0; fi < 4; ++fi)
            #pragma unroll
            for (int ks = 0; ks < 4; ++ks)
                av[fi][ks] = *(const bf16x8*)(ap + fi * 16 * 128 + ks * 32);
    }

    #pragma unroll
    for (int ct = 0; ct < 2; ++ct) {
        bf16x8 wv[4];
        const ushort_t* wp = Wt + (size_t)(ct * 64 + w * 16 + lrow) * 128 + kg * 8;
        #pragma unroll
        for (int ks = 0; ks < 4; ++ks) wv[ks] = *(const bf16x8*)(wp + ks * 32);

        f32x4 acc[4] = {};
        #pragma unroll
        for (int ks = 0; ks < 4; ++ks)
            #pragma unroll
            for (int fi = 0; fi < 4; ++fi)
                acc[fi] = __builtin_amdgcn_mfma_f32_16x16x32_bf16(wv[ks], av[fi][ks], acc[fi], 0, 0, 0);

        int colb = ct * 64 + w * 16 + kg * 4;
        float4 bv4 = *(const float4*)(bias + colb);
        float mcol[4] = {-FLT_MAX, -FLT_MAX, -FLT_MAX, -FLT_MAX};
        #pragma unroll
        for (int fi = 0; fi < 4; ++fi) {
            int lr = lb * 64 + fi * 16 + lrow;
            bool valid = lr < NPGc;
            #pragma unroll
            for (int j = 0; j < 4; ++j) {
                float v = acc[fi][j] + ((const float*)&bv4)[j];
                v = v >= 0.0f ? v : 0.01f * v;
                if (valid) mcol[j] = fmaxf(mcol[j], v);
            }
        }
        #pragma unroll
        for (int j = 0; j < 4; ++j) {
            mcol[j] = fmaxf(mcol[j], __shfl_xor(mcol[j], 1));
            mcol[j] = fmaxf(mcol[j], __shfl_xor(mcol[j], 2));
            mcol[j] = fmaxf(mcol[j], __shfl_xor(mcol[j], 4));
            mcol[j] = fmaxf(mcol[j], __shfl_xor(mcol[j], 8));
        }
        if (lrow == 0) {
            #pragma unroll
            for (int j = 0; j < 4; ++j)
                atomicMaxF(&pools[g * (3 * Dd) + 2 * Dd + colb + j], mcol[j]);
        }
    }
}

// ---- CSR scans + scatter ----
__global__ __launch_bounds__(256) void scan_reduce_kernel(const int* __restrict__ din_i,
                                                          int* __restrict__ partials) {
    int b = blockIdx.x, t = threadIdx.x;
    int base = b * 1024 + t * 4;
    int s = 0;
    #pragma unroll
    for (int j = 0; j < 4; ++j) { int i = base + j; if (i < Nn) s += din_i[i]; }
    #pragma unroll
    for (int off = 32; off > 0; off >>= 1) s += __shfl_xor(s, off);
    __shared__ int wsum[4];
    if ((t & 63) == 0) wsum[t >> 6] = s;
    __syncthreads();
    if (t == 0) partials[b] = wsum[0] + wsum[1] + wsum[2] + wsum[3];
}

__global__ void scan_mid_kernel(int* __restrict__ partials, int* __restrict__ row_start) {
    if (threadIdx.x == 0) {
        int acc = 0;
        for (int i = 0; i < NCHUNK; ++i) { int v = partials[i]; partials[i] = acc; acc += v; }
        row_start[Nn] = acc;
    }
}

__global__ __launch_bounds__(256) void scan_final_kernel(const int* __restrict__ din_i,
                                                         const int* __restrict__ partials,
                                                         int* __restrict__ row_start,
                                                         float* __restrict__ din_f) {
    int b = blockIdx.x, t = threadIdx.x;
    int base = b * 1024 + t * 4;
    int v[4]; int s = 0;
    #pragma unroll
    for (int j = 0; j < 4; ++j) {
        v[j] = (base + j < Nn) ? din_i[base + j] : 0;
        s += v[j];
    }
    __shared__ int buf[256];
    buf[t] = s;
    __syncthreads();
    #pragma unroll
    for (int off = 1; off < 256; off <<= 1) {
        int x = (t >= off) ? buf[t - off] : 0;
        __syncthreads();
        buf[t] += x;
        __syncthreads();
    }
    int excl = buf[t] - s + partials[b];
    #pragma unroll
    for (int j = 0; j < 4; ++j) {
        if (base + j < Nn) {
            row_start[base + j] = excl;
            din_f[base + j] = (float)v[j];
            excl += v[j];
        }
    }
}

__global__ void scatter_kernel(const int* __restrict__ src, const int* __restrict__ dst,
                               const int* __restrict__ row_start, int* __restrict__ cursor,
                               int* __restrict__ csr_src) {
    int e = blockIdx.x * blockDim.x + threadIdx.x;
    if (e >= Ee) return;
    int d = dst[e];
    int slot = row_start[d] + atomicAdd(&cursor[d], 1);
    csr_src[slot] = src[e];
}

// ---- fused GATv2: one wave per dst, 4-edge ILP batch, packed-f32, no-max softmax ----
// hs: dense [N][512] bf16 (cached).  hdres: [N][1024] = [hd|rres] (nt-loaded, once).
__global__ __launch_bounds__(256) void gat_fused_kernel(
    const ushort_t* __restrict__ hs, const ushort_t* __restrict__ hdres,
    const float* __restrict__ attn,
    const int* __restrict__ row_start, const int* __restrict__ csr_src,
    ushort_t* __restrict__ res_bf)
{
    int d = (blockIdx.x * 256 + threadIdx.x) >> 6;
    int lane = threadIdx.x & 63;
    if (d >= Nn) return;
    int e0 = row_start[d], e1 = row_start[d + 1];

    const f32x2 z2 = {0.0f, 0.0f};
    f32x2 hd0, hd1, hd2, hd3, at0, at1, at2, at3;
    {
        u32x4 hr = __builtin_nontemporal_load((const u32x4*)(hdres + (size_t)d * 1024 + lane * 8));
        hd0 = bfpair(hr.x); hd1 = bfpair(hr.y); hd2 = bfpair(hr.z); hd3 = bfpair(hr.w);
        float4 a0 = *(const float4*)(attn + lane * 8);
        float4 a1 = *(const float4*)(attn + lane * 8 + 4);
        at0.x = a0.x; at0.y = a0.y; at1.x = a0.z; at1.y = a0.w;
        at2.x = a1.x; at2.y = a1.y; at3.x = a1.z; at3.y = a1.w;
    }

    float denom = 0.0f;
    f32x2 ac0 = z2, ac1 = z2, ac2 = z2, ac3 = z2;

#define LOGIT_PRE(rr, h0, h1, h2, h3, pout)                                           \
    {                                                                                 \
        h0 = bfpair(rr.x); h1 = bfpair(rr.y); h2 = bfpair(rr.z); h3 = bfpair(rr.w);   \
        f32x2 p2 = z2;                                                                \
        { f32x2 x = h0 + hd0;                                                         \
          p2 += (__builtin_elementwise_max(x, z2) + 0.2f * __builtin_elementwise_min(x, z2)) * at0; } \
        { f32x2 x = h1 + hd1;                                                         \
          p2 += (__builtin_elementwise_max(x, z2) + 0.2f * __builtin_elementwise_min(x, z2)) * at1; } \
        { f32x2 x = h2 + hd2;                                                         \
          p2 += (__builtin_elementwise_max(x, z2) + 0.2f * __builtin_elementwise_min(x, z2)) * at2; } \
        { f32x2 x = h3 + hd3;                                                         \
          p2 += (__builtin_elementwise_max(x, z2) + 0.2f * __builtin_elementwise_min(x, z2)) * at3; } \
        pout = p2.x + p2.y;                                                           \
    }

    int e = e0;
    for (; e + 4 <= e1; e += 4) {
        int sA = csr_src[e], sB = csr_src[e + 1], sC = csr_src[e + 2], sD = csr_src[e + 3];
        uint4 rA = *(const uint4*)(hs + (size_t)sA * HDd + lane * 8);
        uint4 rB = *(const uint4*)(hs + (size_t)sB * HDd + lane * 8);
        uint4 rC = *(const uint4*)(hs + (size_t)sC * HDd + lane * 8);
        uint4 rD = *(const uint4*)(hs + (size_t)sD * HDd + lane * 8);
        f32x2 hA0, hA1, hA2, hA3, hB0, hB1, hB2, hB3;
        f32x2 hC0, hC1, hC2, hC3, hD0, hD1, hD2, hD3;
        float pA, pB, pC, pD;
        LOGIT_PRE(rA, hA0, hA1, hA2, hA3, pA);
        LOGIT_PRE(rB, hB0, hB1, hB2, hB3, pB);
        LOGIT_PRE(rC, hC0, hC1, hC2, hC3, pC);
        LOGIT_PRE(rD, hD0, hD1, hD2, hD3, pD);
        pA += __shfl_xor(pA, 1); pB += __shfl_xor(pB, 1); pC += __shfl_xor(pC, 1); pD += __shfl_xor(pD, 1);
        pA += __shfl_xor(pA, 2); pB += __shfl_xor(pB, 2); pC += __shfl_xor(pC, 2); pD += __shfl_xor(pD, 2);
        pA += __shfl_xor(pA, 4); pB += __shfl_xor(pB, 4); pC += __shfl_xor(pC, 4); pD += __shfl_xor(pD, 4);
        pA += __shfl_xor(pA, 8); pB += __shfl_xor(pB, 8); pC += __shfl_xor(pC, 8); pD += __shfl_xor(pD, 8);
        float exA = __expf(fminf(fmaxf(pA, -40.0f), 40.0f));
        float exB = __expf(fminf(fmaxf(pB, -40.0f), 40.0f));
        float exC = __expf(fminf(fmaxf(pC, -40.0f), 40.0f));
        float exD = __expf(fminf(fmaxf(pD, -40.0f), 40.0f));
        denom += (exA + exB) + (exC + exD);
        ac0 += hA0 * exA + hB0 * exB + hC0 * exC + hD0 * exD;
        ac1 += hA1 * exA + hB1 * exB + hC1 * exC + hD1 * exD;
        ac2 += hA2 * exA + hB2 * exB + hC2 * exC + hD2 * exD;
        ac3 += hA3 * exA + hB3 * exB + hC3 * exC + hD3 * exD;
    }
    for (; e < e1; ++e) {
        int s = csr_src[e];
        uint4 rr = *(const uint4*)(hs + (size_t)s * HDd + lane * 8);
        f32x2 h0, h1, h2, h3;
        float p;
        LOGIT_PRE(rr, h0, h1, h2, h3, p);
        p += __shfl_xor(p, 1); p += __shfl_xor(p, 2);
        p += __shfl_xor(p, 4); p += __shfl_xor(p, 8);
        float ex = __expf(fminf(fmaxf(p, -40.0f), 40.0f));
        denom += ex;
        ac0 += h0 * ex; ac1 += h1 * ex; ac2 += h2 * ex; ac3 += h3 * ex;
    }
#undef LOGIT_PRE

    float inv = (e1 > e0) ? 1.0f / denom : 0.0f;
    f32x2 rv0, rv1, rv2, rv3;
    {
        u32x4 rr = __builtin_nontemporal_load((const u32x4*)(hdres + (size_t)d * 1024 + 512 + lane * 8));
        rv0 = bfpair(rr.x); rv1 = bfpair(rr.y); rv2 = bfpair(rr.z); rv3 = bfpair(rr.w);
    }
    float t[8];
    {
        f32x2 v0 = ac0 * inv + rv0, v1 = ac1 * inv + rv1;
        f32x2 v2 = ac2 * inv + rv2, v3 = ac3 * inv + rv3;
        f32x2 l0 = __builtin_elementwise_max(v0, z2) + 0.01f * __builtin_elementwise_min(v0, z2);
        f32x2 l1 = __builtin_elementwise_max(v1, z2) + 0.01f * __builtin_elementwise_min(v1, z2);
        f32x2 l2 = __builtin_elementwise_max(v2, z2) + 0.01f * __builtin_elementwise_min(v2, z2);
        f32x2 l3 = __builtin_elementwise_max(v3, z2) + 0.01f * __builtin_elementwise_min(v3, z2);
        t[0] = l0.x; t[1] = l0.y; t[2] = l1.x; t[3] = l1.y;
        t[4] = l2.x; t[5] = l2.y; t[6] = l3.x; t[7] = l3.y;
    }
    #pragma unroll
    for (int j = 0; j < 8; ++j) {
        t[j] += __shfl_xor(t[j], 16);
        t[j] += __shfl_xor(t[j], 32);
    }
    if (lane < 16) {
        float o0 = 0.25f * t[0], o1 = 0.25f * t[1], o2 = 0.25f * t[2], o3 = 0.25f * t[3];
        float o4 = 0.25f * t[4], o5 = 0.25f * t[5], o6 = 0.25f * t[6], o7 = 0.25f * t[7];
        unsigned q0, q1, q2, q3;
        asm("v_cvt_pk_bf16_f32 %0, %1, %2" : "=v"(q0) : "v"(o0), "v"(o1));
        asm("v_cvt_pk_bf16_f32 %0, %1, %2" : "=v"(q1) : "v"(o2), "v"(o3));
        asm("v_cvt_pk_bf16_f32 %0, %1, %2" : "=v"(q2) : "v"(o4), "v"(o5));
        asm("v_cvt_pk_bf16_f32 %0, %1, %2" : "=v"(q3) : "v"(o6), "v"(o7));
        uint4 qb; qb.x = q0; qb.y = q1; qb.z = q2; qb.w = q3;
        *(uint4*)(res_bf + (size_t)d * Dd + lane * 8) = qb;
    }
}

// ---- GraphConv aggregate via CSR, bf16 gather, 2-deep prefetch ----
__global__ __launch_bounds__(256) void gc_gather_kernel(
    const ushort_t* __restrict__ res_bf, const int* __restrict__ row_start,
    const int* __restrict__ csr_src, const float* __restrict__ dout,
    const float* __restrict__ din, ushort_t* __restrict__ agg_bf)
{
    int d = (blockIdx.x * 256 + threadIdx.x) >> 6;
    int lane = threadIdx.x & 63;
    if (d >= Nn) return;
    int e0 = row_start[d], e1 = row_start[d + 1];
    const f32x2 z2 = {0.0f, 0.0f};
    f32x2 a2 = z2;
    int s0 = (e0 < e1) ? csr_src[e0] : 0;
    int s1 = (e0 + 1 < e1) ? csr_src[e0 + 1] : s0;
    float sc0 = 1.0f / sqrtf(fmaxf((e0 < e1) ? dout[s0] : 1.0f, 1.0f));
    float sc1 = 1.0f / sqrtf(fmaxf((e0 + 1 < e1) ? dout[s1] : 1.0f, 1.0f));
    unsigned u0 = *(const unsigned*)(res_bf + (size_t)s0 * Dd + lane * 2);
    unsigned u1 = *(const unsigned*)(res_bf + (size_t)s1 * Dd + lane * 2);
    for (int e = e0; e < e1; ++e) {
        int s2 = (e + 2 < e1) ? csr_src[e + 2] : s0;
        float sc2 = 1.0f / sqrtf(fmaxf(dout[s2], 1.0f));
        unsigned u2 = *(const unsigned*)(res_bf + (size_t)s2 * Dd + lane * 2);
        a2 += bfpair(u0) * sc0;
        u0 = u1; u1 = u2; sc0 = sc1; sc1 = sc2;
    }
    float scd = 1.0f / sqrtf(fmaxf(din[d], 1.0f));
    float ax = a2.x * scd, ay = a2.y * scd;
    unsigned q;
    asm("v_cvt_pk_bf16_f32 %0, %1, %2" : "=v"(q) : "v"(ax), "v"(ay));
    *(unsigned*)(agg_bf + (size_t)d * Dd + lane * 2) = q;
}

__global__ void final_kernel(const float* __restrict__ pools, const float* __restrict__ W_mlp,
                             const float* __restrict__ b_mlp, float* __restrict__ out) {
    int b = blockIdx.x, lane = threadIdx.x;
    float s = 0.0f;
    for (int j = lane; j < 3 * Dd; j += 64)
        s += fmaxf(pools[b * (3 * Dd) + j], 0.0f) * W_mlp[j];
    #pragma unroll
    for (int off = 32; off > 0; off >>= 1) s += __shfl_xor(s, off);
    if (lane == 0) out[b] = s + b_mlp[0];
}

extern "C" void kernel_launch(void* const* d_in, const int* in_sizes, int n_in,
                              void* d_out, int out_size, void* d_ws, size_t ws_size,
                              hipStream_t stream) {
    const int*   node_ids = (const int*)d_in[0];
    const int*   src      = (const int*)d_in[1];
    const int*   dst      = (const int*)d_in[2];
    const float* emb      = (const float*)d_in[3];
    const float* W_src    = (const float*)d_in[4];
    const float* b_src    = (const float*)d_in[5];
    const float* W_dst    = (const float*)d_in[6];
    const float* b_dst    = (const float*)d_in[7];
    const float* attn     = (const float*)d_in[8];
    const float* W_res    = (const float*)d_in[9];
    const float* b_res    = (const float*)d_in[10];
    const float* W_gc     = (const float*)d_in[11];
    const float* b_gc     = (const float*)d_in[12];
    const float* W_mlp    = (const float*)d_in[13];
    const float* b_mlp    = (const float*)d_in[14];
    float* out = (float*)d_out;

    char* w = (char*)d_ws;
    size_t off = 0;
    ushort_t* feat_bf = (ushort_t*)(w + off); off += (size_t)(Nn + 64) * Dd * 2;  // 12.8 MB (+pad)
    ushort_t* hs_buf  = (ushort_t*)(w + off); off += (size_t)Nn * HDd * 2;        // 51.2 MB
    ushort_t* hdres   = (ushort_t*)(w + off); off += (size_t)Nn * 1024 * 2;       // 102.4 MB
    ushort_t* Wt      = (ushort_t*)(w + off); off += (size_t)WNf * 128 * 2;
    ushort_t* Wt_gc   = (ushort_t*)(w + off); off += (size_t)128 * 128 * 2;
    float*    bias_f  = (float*)(w + off);    off += (size_t)WNf * 4;
    int*      csr_src = (int*)(w + off);      off += (size_t)Ee * 4;
    int*      row_st  = (int*)(w + off);      off += ((size_t)Nn + 4) * 4;
    // cursor | din_i | dout_f contiguous: single memset zeroes all three
    int*      cursor  = (int*)(w + off);      off += (size_t)Nn * 4;
    int*      din_i   = (int*)(w + off);      off += (size_t)Nn * 4;
    float*    dout_f  = (float*)(w + off);    off += (size_t)Nn * 4;
    float*    din_f   = (float*)(w + off);    off += (size_t)Nn * 4;
    int*      partials= (int*)(w + off);      off += 64 * 4;
    float*    pools   = (float*)(w + off);    off += (size_t)Bg * 3 * Dd * 4;
    ushort_t* res_bf  = (ushort_t*)(w + off); off += (size_t)Nn * Dd * 2;         // 12.8 MB

    ushort_t* agg_bf = hs_buf;                                // hs dead after gat_fused

    hipMemsetAsync(cursor, 0, (size_t)3 * Nn * 4, stream);    // cursor + din_i + dout_f

    setup_kernel<<<(Nn * 32) / 256, 256, 0, stream>>>(
        node_ids, emb, feat_bf, src, dst, W_src, W_dst, W_res, W_gc,
        b_src, b_dst, b_res, Wt, Wt_gc, bias_f,
        din_i, dout_f, pools);
    maxpool_bf_kernel<<<dim3(Bg, 50), 64, 0, stream>>>(feat_bf, pools, 0);

    // CSR build (degrees already accumulated in setup)
    scan_reduce_kernel<<<NCHUNK, 256, 0, stream>>>(din_i, partials);
    scan_mid_kernel<<<1, 64, 0, stream>>>(partials, row_st);
    scan_final_kernel<<<NCHUNK, 256, 0, stream>>>(din_i, partials, row_st, din_f);
    scatter_kernel<<<(Ee + 255) / 256, 256, 0, stream>>>(src, dst, row_st, cursor, csr_src);

    // merged hs|hd|rres GEMM: grid 9384 = 782 rows x 12 col-splits (cached stores)
    mfma_gemm_kernel<<<((Nn + 63) / 64) * NCS, 256, 0, stream>>>(
        feat_bf, Wt, bias_f, hs_buf, hdres, Nn);

    gat_fused_kernel<<<(Nn * 64) / 256, 256, 0, stream>>>(
        hs_buf, hdres, attn, row_st, csr_src, res_bf);
    maxpool_bf_kernel<<<dim3(Bg, 50), 64, 0, stream>>>(res_bf, pools, Dd);

    gc_gather_kernel<<<(Nn * 64) / 256, 256, 0, stream>>>(res_bf, row_st, csr_src, dout_f, din_f, agg_bf);
    mfma_gc_pool_kernel<<<Bg * 98, 256, 0, stream>>>(agg_bf, Wt_gc, b_gc, pools);

    final_kernel<<<Bg, 64, 0, stream>>>(pools, W_mlp, b_mlp, out);
}

// Round 19
// 336.354 us; speedup vs baseline: 1.1250x; 1.1250x over previous
//
#include <hip/hip_runtime.h>
#include <float.h>
#include <math.h>

#define Bg   8
#define NPGc 6250
#define Hh   4
#define Dd   128
#define Nn   50000
#define Ee   400000
#define HDd  512
#define WNf  1536   // hs(512) | hd(512) | rres(512) column space
#define NCHUNK 49   // ceil(50000/1024)

typedef unsigned short ushort_t;
typedef __attribute__((ext_vector_type(8))) short bf16x8;
typedef __attribute__((ext_vector_type(4))) float f32x4;
typedef __attribute__((ext_vector_type(2))) float f32x2;
typedef __attribute__((ext_vector_type(4))) unsigned u32x4;

__device__ __forceinline__ void atomicMaxF(float* addr, float val) {
    if (val >= 0.0f) atomicMax((int*)addr, __float_as_int(val));
    else             atomicMin((unsigned int*)addr, __float_as_uint(val));
}

__device__ __forceinline__ ushort_t f2bf(float x) {
    unsigned u = __float_as_uint(x);
    unsigned r = (u + 0x7FFFu + ((u >> 16) & 1u)) >> 16;   // RNE
    return (ushort_t)r;
}

__device__ __forceinline__ f32x2 bfpair(unsigned u) {
    f32x2 r;
    r.x = __uint_as_float(u << 16);
    r.y = __uint_as_float(u & 0xFFFF0000u);
    return r;
}

// ---- fused setup: gather(bf16) | degree histograms | weight prep | pools init ----
// REQUIRES: cursor|din_i|dout_f zeroed via hipMemsetAsync before launch.
__global__ void setup_kernel(const int* __restrict__ ids, const float* __restrict__ emb,
                             ushort_t* __restrict__ feat_bf,
                             const int* __restrict__ src, const int* __restrict__ dst,
                             const float* __restrict__ W_src, const float* __restrict__ W_dst,
                             const float* __restrict__ W_res, const float* __restrict__ W_gc,
                             const float* __restrict__ b_src, const float* __restrict__ b_dst,
                             const float* __restrict__ b_res,
                             ushort_t* __restrict__ Wt, ushort_t* __restrict__ Wt_gc,
                             float* __restrict__ bias_f,
                             int* __restrict__ din_i, float* __restrict__ dout,
                             float* __restrict__ pools) {
    int i = blockIdx.x * blockDim.x + threadIdx.x;
    {   // gather: over N*32 float4s -> bf16
        int n = i >> 5, c = i & 31;
        int id = ids[n];
        float4 v = ((const float4*)emb)[(size_t)id * 32 + c];
        ushort4 b;
        b.x = f2bf(v.x); b.y = f2bf(v.y); b.z = f2bf(v.z); b.w = f2bf(v.w);
        ((ushort4*)feat_bf)[(size_t)n * 32 + c] = b;
    }
    if (i < Ee) {   // degree histograms (buffers pre-zeroed by memset)
        atomicAdd(&din_i[dst[i]], 1);
        atomicAdd(&dout[src[i]], 1.0f);
    }
    if (i < Bg * 3 * Dd) pools[i] = -FLT_MAX;
    if (i < WNf * 128) {
        int c = i >> 7, k = i & 127;
        float v = (c < 512) ? W_src[k * 512 + c]
                : (c < 1024) ? W_dst[k * 512 + (c - 512)]
                             : W_res[k * 512 + (c - 1024)];
        Wt[i] = f2bf(v);
    } else if (i < WNf * 128 + 128 * 128) {
        int j = i - WNf * 128;
        int c = j >> 7, k = j & 127;
        Wt_gc[j] = f2bf(W_gc[k * 128 + c]);
    }
    if (i < WNf)
        bias_f[i] = (i < 512) ? b_src[i] : (i < 1024) ? b_dst[i - 512] : b_res[i - 1024];
}

// bf16 maxpool; 64 threads, 2 cols/lane
__global__ void maxpool_bf_kernel(const ushort_t* __restrict__ x, float* __restrict__ pools, int col_off) {
    int b = blockIdx.x, chunk = blockIdx.y, lane = threadIdx.x;   // 64 threads
    int i0 = chunk * 125;
    f32x2 mx = {-FLT_MAX, -FLT_MAX};
    for (int i = 0; i < 125; ++i) {
        unsigned u = *(const unsigned*)(x + ((size_t)(b * NPGc + i0 + i)) * Dd + lane * 2);
        mx = __builtin_elementwise_max(mx, bfpair(u));
    }
    atomicMaxF(&pools[b * (3 * Dd) + col_off + lane * 2],     mx.x);
    atomicMaxF(&pools[b * (3 * Dd) + col_off + lane * 2 + 1], mx.y);
}

// ---- merged MFMA GEMM: 24 col-tiles; tiles 0-7 -> hs_buf, tiles 8-23 -> hdres.
// GNT=3/NCS=8 (R18 post-mortem: GNT=2/NCS=12 was the 92->112us regression --
// per-block A-prologue amortized over too few tiles).  Cached stores.
// XCD-locality swizzle (grid 6256 = 782 x 8), LDS-coalesced epilogue.
#define GNT 3
#define NCS 8
__global__ __launch_bounds__(256) void mfma_gemm_kernel(
    const ushort_t* __restrict__ A, const ushort_t* __restrict__ Wt,
    const float* __restrict__ bias, ushort_t* __restrict__ Ohs,
    ushort_t* __restrict__ Odr, int n_rows)
{
    __shared__ ushort_t Cs[2][64 * 64];
    int bid = blockIdx.x;
    int lin = (bid & 7) * (gridDim.x >> 3) + (bid >> 3);
    int row0 = (lin / NCS) * 64;
    int ct0  = (lin % NCS) * GNT;
    int w = threadIdx.x >> 6, lane = threadIdx.x & 63;
    int lrow = lane & 15, kg = lane >> 4;

    bf16x8 av[4][4];
    {
        const ushort_t* ap = A + (size_t)(row0 + lrow) * 128 + kg * 8;
        #pragma unroll
        for (int fi = 0; fi < 4; ++fi)
            #pragma unroll
            for (int ks = 0; ks < 4; ++ks)
                av[fi][ks] = *(const bf16x8*)(ap + fi * 16 * 128 + ks * 32);
    }
    bf16x8 wv[GNT][4];
    float4 bv[GNT];
    {
        const ushort_t* wp = Wt + (size_t)(ct0 * 64 + w * 16 + lrow) * 128 + kg * 8;
        #pragma unroll
        for (int ct = 0; ct < GNT; ++ct) {
            #pragma unroll
            for (int ks = 0; ks < 4; ++ks)
                wv[ct][ks] = *(const bf16x8*)(wp + (size_t)ct * 8192 + ks * 32);
            bv[ct] = *(const float4*)(bias + (ct0 + ct) * 64 + w * 16 + kg * 4);
        }
    }

    #pragma unroll
    for (int ct = 0; ct < GNT; ++ct) {
        f32x4 acc[4] = {};
        #pragma unroll
        for (int ks = 0; ks < 4; ++ks)
            #pragma unroll
            for (int fi = 0; fi < 4; ++fi)
                acc[fi] = __builtin_amdgcn_mfma_f32_16x16x32_bf16(wv[ct][ks], av[fi][ks], acc[fi], 0, 0, 0);

        ushort_t* cb = Cs[ct & 1];
        int cbase = w * 32 + kg * 8;
        #pragma unroll
        for (int fi = 0; fi < 4; ++fi) {
            float o0 = acc[fi][0] + bv[ct].x;
            float o1 = acc[fi][1] + bv[ct].y;
            float o2 = acc[fi][2] + bv[ct].z;
            float o3 = acc[fi][3] + bv[ct].w;
            unsigned q0, q1;
            asm("v_cvt_pk_bf16_f32 %0, %1, %2" : "=v"(q0) : "v"(o0), "v"(o1));
            asm("v_cvt_pk_bf16_f32 %0, %1, %2" : "=v"(q1) : "v"(o2), "v"(o3));
            int r = fi * 16 + lrow;
            int cbyte = cbase ^ ((r & 7) << 4);
            uint2 q; q.x = q0; q.y = q1;
            *(uint2*)((char*)cb + r * 128 + cbyte) = q;
        }
        __syncthreads();
        {
            int t = threadIdx.x;
            const char* cbr = (const char*)cb;
            int gcol = (ct0 + ct) * 64;
            char* ob; int wn;
            if (gcol < 512) { ob = (char*)Ohs; wn = 512; }
            else            { ob = (char*)Odr; wn = 1024; gcol -= 512; }
            #pragma unroll
            for (int h = 0; h < 2; ++h) {
                int r  = (h * 256 + t) >> 3;
                int ch = t & 7;
                int cbyte = (ch * 16) ^ ((r & 7) << 4);
                u32x4 v = *(const u32x4*)(cbr + r * 128 + cbyte);
                int grow = row0 + r;
                if (grow < n_rows)
                    *(u32x4*)(ob + ((size_t)grow * wn + gcol) * 2 + ch * 16) = v;
            }
        }
    }
}

// ---- GraphConv GEMM fused with maxpool2 ----
__global__ __launch_bounds__(256) void mfma_gc_pool_kernel(
    const ushort_t* __restrict__ A, const ushort_t* __restrict__ Wt,
    const float* __restrict__ bias, float* __restrict__ pools)
{
    int g = blockIdx.x / 98, lb = blockIdx.x % 98;
    int row0 = g * NPGc + lb * 64;
    int w = threadIdx.x >> 6, lane = threadIdx.x & 63;
    int lrow = lane & 15, kg = lane >> 4;

    bf16x8 av[4][4];
    {
        const ushort_t* ap = A + (size_t)(row0 + lrow) * 128 + kg * 8;
        #pragma unroll
        for (int fi = 0; fi < 4; ++fi)
            #pragma unroll
            for (int ks = 0; ks < 4; ++ks)
                av[fi][ks] = *(const bf16x8*)(ap + fi * 16 * 128 + ks * 32);
    }

    #pragma unroll
    for (int ct = 0; ct < 2; ++ct) {
        bf16x8 wv[4];
        const ushort_t* wp = Wt + (size_t)(ct * 64 + w * 16 + lrow) * 128 + kg * 8;
        #pragma unroll
        for (int ks = 0; ks < 4; ++ks) wv[ks] = *(const bf16x8*)(wp + ks * 32);

        f32x4 acc[4] = {};
        #pragma unroll
        for (int ks = 0; ks < 4; ++ks)
            #pragma unroll
            for (int fi = 0; fi < 4; ++fi)
                acc[fi] = __builtin_amdgcn_mfma_f32_16x16x32_bf16(wv[ks], av[fi][ks], acc[fi], 0, 0, 0);

        int colb = ct * 64 + w * 16 + kg * 4;
        float4 bv4 = *(const float4*)(bias + colb);
        float mcol[4] = {-FLT_MAX, -FLT_MAX, -FLT_MAX, -FLT_MAX};
        #pragma unroll
        for (int fi = 0; fi < 4; ++fi) {
            int lr = lb * 64 + fi * 16 + lrow;
            bool valid = lr < NPGc;
            #pragma unroll
            for (int j = 0; j < 4; ++j) {
                float v = acc[fi][j] + ((const float*)&bv4)[j];
                v = v >= 0.0f ? v : 0.01f * v;
                if (valid) mcol[j] = fmaxf(mcol[j], v);
            }
        }
        #pragma unroll
        for (int j = 0; j < 4; ++j) {
            mcol[j] = fmaxf(mcol[j], __shfl_xor(mcol[j], 1));
            mcol[j] = fmaxf(mcol[j], __shfl_xor(mcol[j], 2));
            mcol[j] = fmaxf(mcol[j], __shfl_xor(mcol[j], 4));
            mcol[j] = fmaxf(mcol[j], __shfl_xor(mcol[j], 8));
        }
        if (lrow == 0) {
            #pragma unroll
            for (int j = 0; j < 4; ++j)
                atomicMaxF(&pools[g * (3 * Dd) + 2 * Dd + colb + j], mcol[j]);
        }
    }
}

// ---- CSR scans + scatter ----
__global__ __launch_bounds__(256) void scan_reduce_kernel(const int* __restrict__ din_i,
                                                          int* __restrict__ partials) {
    int b = blockIdx.x, t = threadIdx.x;
    int base = b * 1024 + t * 4;
    int s = 0;
    #pragma unroll
    for (int j = 0; j < 4; ++j) { int i = base + j; if (i < Nn) s += din_i[i]; }
    #pragma unroll
    for (int off = 32; off > 0; off >>= 1) s += __shfl_xor(s, off);
    __shared__ int wsum[4];
    if ((t & 63) == 0) wsum[t >> 6] = s;
    __syncthreads();
    if (t == 0) partials[b] = wsum[0] + wsum[1] + wsum[2] + wsum[3];
}

__global__ void scan_mid_kernel(int* __restrict__ partials, int* __restrict__ row_start) {
    if (threadIdx.x == 0) {
        int acc = 0;
        for (int i = 0; i < NCHUNK; ++i) { int v = partials[i]; partials[i] = acc; acc += v; }
        row_start[Nn] = acc;
    }
}

__global__ __launch_bounds__(256) void scan_final_kernel(const int* __restrict__ din_i,
                                                         const int* __restrict__ partials,
                                                         int* __restrict__ row_start,
                                                         float* __restrict__ din_f) {
    int b = blockIdx.x, t = threadIdx.x;
    int base = b * 1024 + t * 4;
    int v[4]; int s = 0;
    #pragma unroll
    for (int j = 0; j < 4; ++j) {
        v[j] = (base + j < Nn) ? din_i[base + j] : 0;
        s += v[j];
    }
    __shared__ int buf[256];
    buf[t] = s;
    __syncthreads();
    #pragma unroll
    for (int off = 1; off < 256; off <<= 1) {
        int x = (t >= off) ? buf[t - off] : 0;
        __syncthreads();
        buf[t] += x;
        __syncthreads();
    }
    int excl = buf[t] - s + partials[b];
    #pragma unroll
    for (int j = 0; j < 4; ++j) {
        if (base + j < Nn) {
            row_start[base + j] = excl;
            din_f[base + j] = (float)v[j];
            excl += v[j];
        }
    }
}

__global__ void scatter_kernel(const int* __restrict__ src, const int* __restrict__ dst,
                               const int* __restrict__ row_start, int* __restrict__ cursor,
                               int* __restrict__ csr_src) {
    int e = blockIdx.x * blockDim.x + threadIdx.x;
    if (e >= Ee) return;
    int d = dst[e];
    int slot = row_start[d] + atomicAdd(&cursor[d], 1);
    csr_src[slot] = src[e];
}

// ---- fused GATv2: one wave per dst, 4-edge ILP batch, packed-f32, no-max softmax ----
// hs: dense [N][512] bf16 (cached).  hdres: [N][1024] = [hd|rres] (nt-loaded, once).
__global__ __launch_bounds__(256) void gat_fused_kernel(
    const ushort_t* __restrict__ hs, const ushort_t* __restrict__ hdres,
    const float* __restrict__ attn,
    const int* __restrict__ row_start, const int* __restrict__ csr_src,
    ushort_t* __restrict__ res_bf)
{
    int d = (blockIdx.x * 256 + threadIdx.x) >> 6;
    int lane = threadIdx.x & 63;
    if (d >= Nn) return;
    int e0 = row_start[d], e1 = row_start[d + 1];

    const f32x2 z2 = {0.0f, 0.0f};
    f32x2 hd0, hd1, hd2, hd3, at0, at1, at2, at3;
    {
        u32x4 hr = __builtin_nontemporal_load((const u32x4*)(hdres + (size_t)d * 1024 + lane * 8));
        hd0 = bfpair(hr.x); hd1 = bfpair(hr.y); hd2 = bfpair(hr.z); hd3 = bfpair(hr.w);
        float4 a0 = *(const float4*)(attn + lane * 8);
        float4 a1 = *(const float4*)(attn + lane * 8 + 4);
        at0.x = a0.x; at0.y = a0.y; at1.x = a0.z; at1.y = a0.w;
        at2.x = a1.x; at2.y = a1.y; at3.x = a1.z; at3.y = a1.w;
    }

    float denom = 0.0f;
    f32x2 ac0 = z2, ac1 = z2, ac2 = z2, ac3 = z2;

#define LOGIT_PRE(rr, h0, h1, h2, h3, pout)                                           \
    {                                                                                 \
        h0 = bfpair(rr.x); h1 = bfpair(rr.y); h2 = bfpair(rr.z); h3 = bfpair(rr.w);   \
        f32x2 p2 = z2;                                                                \
        { f32x2 x = h0 + hd0;                                                         \
          p2 += (__builtin_elementwise_max(x, z2) + 0.2f * __builtin_elementwise_min(x, z2)) * at0; } \
        { f32x2 x = h1 + hd1;                                                         \
          p2 += (__builtin_elementwise_max(x, z2) + 0.2f * __builtin_elementwise_min(x, z2)) * at1; } \
        { f32x2 x = h2 + hd2;                                                         \
          p2 += (__builtin_elementwise_max(x, z2) + 0.2f * __builtin_elementwise_min(x, z2)) * at2; } \
        { f32x2 x = h3 + hd3;                                                         \
          p2 += (__builtin_elementwise_max(x, z2) + 0.2f * __builtin_elementwise_min(x, z2)) * at3; } \
        pout = p2.x + p2.y;                                                           \
    }

    int e = e0;
    for (; e + 4 <= e1; e += 4) {
        int sA = csr_src[e], sB = csr_src[e + 1], sC = csr_src[e + 2], sD = csr_src[e + 3];
        uint4 rA = *(const uint4*)(hs + (size_t)sA * HDd + lane * 8);
        uint4 rB = *(const uint4*)(hs + (size_t)sB * HDd + lane * 8);
        uint4 rC = *(const uint4*)(hs + (size_t)sC * HDd + lane * 8);
        uint4 rD = *(const uint4*)(hs + (size_t)sD * HDd + lane * 8);
        f32x2 hA0, hA1, hA2, hA3, hB0, hB1, hB2, hB3;
        f32x2 hC0, hC1, hC2, hC3, hD0, hD1, hD2, hD3;
        float pA, pB, pC, pD;
        LOGIT_PRE(rA, hA0, hA1, hA2, hA3, pA);
        LOGIT_PRE(rB, hB0, hB1, hB2, hB3, pB);
        LOGIT_PRE(rC, hC0, hC1, hC2, hC3, pC);
        LOGIT_PRE(rD, hD0, hD1, hD2, hD3, pD);
        pA += __shfl_xor(pA, 1); pB += __shfl_xor(pB, 1); pC += __shfl_xor(pC, 1); pD += __shfl_xor(pD, 1);
        pA += __shfl_xor(pA, 2); pB += __shfl_xor(pB, 2); pC += __shfl_xor(pC, 2); pD += __shfl_xor(pD, 2);
        pA += __shfl_xor(pA, 4); pB += __shfl_xor(pB, 4); pC += __shfl_xor(pC, 4); pD += __shfl_xor(pD, 4);
        pA += __shfl_xor(pA, 8); pB += __shfl_xor(pB, 8); pC += __shfl_xor(pC, 8); pD += __shfl_xor(pD, 8);
        float exA = __expf(fminf(fmaxf(pA, -40.0f), 40.0f));
        float exB = __expf(fminf(fmaxf(pB, -40.0f), 40.0f));
        float exC = __expf(fminf(fmaxf(pC, -40.0f), 40.0f));
        float exD = __expf(fminf(fmaxf(pD, -40.0f), 40.0f));
        denom += (exA + exB) + (exC + exD);
        ac0 += hA0 * exA + hB0 * exB + hC0 * exC + hD0 * exD;
        ac1 += hA1 * exA + hB1 * exB + hC1 * exC + hD1 * exD;
        ac2 += hA2 * exA + hB2 * exB + hC2 * exC + hD2 * exD;
        ac3 += hA3 * exA + hB3 * exB + hC3 * exC + hD3 * exD;
    }
    for (; e < e1; ++e) {
        int s = csr_src[e];
        uint4 rr = *(const uint4*)(hs + (size_t)s * HDd + lane * 8);
        f32x2 h0, h1, h2, h3;
        float p;
        LOGIT_PRE(rr, h0, h1, h2, h3, p);
        p += __shfl_xor(p, 1); p += __shfl_xor(p, 2);
        p += __shfl_xor(p, 4); p += __shfl_xor(p, 8);
        float ex = __expf(fminf(fmaxf(p, -40.0f), 40.0f));
        denom += ex;
        ac0 += h0 * ex; ac1 += h1 * ex; ac2 += h2 * ex; ac3 += h3 * ex;
    }
#undef LOGIT_PRE

    float inv = (e1 > e0) ? 1.0f / denom : 0.0f;
    f32x2 rv0, rv1, rv2, rv3;
    {
        u32x4 rr = __builtin_nontemporal_load((const u32x4*)(hdres + (size_t)d * 1024 + 512 + lane * 8));
        rv0 = bfpair(rr.x); rv1 = bfpair(rr.y); rv2 = bfpair(rr.z); rv3 = bfpair(rr.w);
    }
    float t[8];
    {
        f32x2 v0 = ac0 * inv + rv0, v1 = ac1 * inv + rv1;
        f32x2 v2 = ac2 * inv + rv2, v3 = ac3 * inv + rv3;
        f32x2 l0 = __builtin_elementwise_max(v0, z2) + 0.01f * __builtin_elementwise_min(v0, z2);
        f32x2 l1 = __builtin_elementwise_max(v1, z2) + 0.01f * __builtin_elementwise_min(v1, z2);
        f32x2 l2 = __builtin_elementwise_max(v2, z2) + 0.01f * __builtin_elementwise_min(v2, z2);
        f32x2 l3 = __builtin_elementwise_max(v3, z2) + 0.01f * __builtin_elementwise_min(v3, z2);
        t[0] = l0.x; t[1] = l0.y; t[2] = l1.x; t[3] = l1.y;
        t[4] = l2.x; t[5] = l2.y; t[6] = l3.x; t[7] = l3.y;
    }
    #pragma unroll
    for (int j = 0; j < 8; ++j) {
        t[j] += __shfl_xor(t[j], 16);
        t[j] += __shfl_xor(t[j], 32);
    }
    if (lane < 16) {
        float o0 = 0.25f * t[0], o1 = 0.25f * t[1], o2 = 0.25f * t[2], o3 = 0.25f * t[3];
        float o4 = 0.25f * t[4], o5 = 0.25f * t[5], o6 = 0.25f * t[6], o7 = 0.25f * t[7];
        unsigned q0, q1, q2, q3;
        asm("v_cvt_pk_bf16_f32 %0, %1, %2" : "=v"(q0) : "v"(o0), "v"(o1));
        asm("v_cvt_pk_bf16_f32 %0, %1, %2" : "=v"(q1) : "v"(o2), "v"(o3));
        asm("v_cvt_pk_bf16_f32 %0, %1, %2" : "=v"(q2) : "v"(o4), "v"(o5));
        asm("v_cvt_pk_bf16_f32 %0, %1, %2" : "=v"(q3) : "v"(o6), "v"(o7));
        uint4 qb; qb.x = q0; qb.y = q1; qb.z = q2; qb.w = q3;
        *(uint4*)(res_bf + (size_t)d * Dd + lane * 8) = qb;
    }
}

// ---- GraphConv aggregate via CSR, bf16 gather, 4-edge ILP batch ----
__global__ __launch_bounds__(256) void gc_gather_kernel(
    const ushort_t* __restrict__ res_bf, const int* __restrict__ row_start,
    const int* __restrict__ csr_src, const float* __restrict__ dout,
    const float* __restrict__ din, ushort_t* __restrict__ agg_bf)
{
    int d = (blockIdx.x * 256 + threadIdx.x) >> 6;
    int lane = threadIdx.x & 63;
    if (d >= Nn) return;
    int e0 = row_start[d], e1 = row_start[d + 1];
    const f32x2 z2 = {0.0f, 0.0f};
    f32x2 a2 = z2;
    int e = e0;
    for (; e + 4 <= e1; e += 4) {
        int s0 = csr_src[e],     s1 = csr_src[e + 1];
        int s2 = csr_src[e + 2], s3 = csr_src[e + 3];
        float c0 = 1.0f / sqrtf(fmaxf(dout[s0], 1.0f));
        float c1 = 1.0f / sqrtf(fmaxf(dout[s1], 1.0f));
        float c2 = 1.0f / sqrtf(fmaxf(dout[s2], 1.0f));
        float c3 = 1.0f / sqrtf(fmaxf(dout[s3], 1.0f));
        unsigned u0 = *(const unsigned*)(res_bf + (size_t)s0 * Dd + lane * 2);
        unsigned u1 = *(const unsigned*)(res_bf + (size_t)s1 * Dd + lane * 2);
        unsigned u2 = *(const unsigned*)(res_bf + (size_t)s2 * Dd + lane * 2);
        unsigned u3 = *(const unsigned*)(res_bf + (size_t)s3 * Dd + lane * 2);
        a2 += bfpair(u0) * c0 + bfpair(u1) * c1 + bfpair(u2) * c2 + bfpair(u3) * c3;
    }
    for (; e < e1; ++e) {
        int s = csr_src[e];
        float c = 1.0f / sqrtf(fmaxf(dout[s], 1.0f));
        unsigned u = *(const unsigned*)(res_bf + (size_t)s * Dd + lane * 2);
        a2 += bfpair(u) * c;
    }
    float scd = 1.0f / sqrtf(fmaxf(din[d], 1.0f));
    float ax = a2.x * scd, ay = a2.y * scd;
    unsigned q;
    asm("v_cvt_pk_bf16_f32 %0, %1, %2" : "=v"(q) : "v"(ax), "v"(ay));
    *(unsigned*)(agg_bf + (size_t)d * Dd + lane * 2) = q;
}

__global__ void final_kernel(const float* __restrict__ pools, const float* __restrict__ W_mlp,
                             const float* __restrict__ b_mlp, float* __restrict__ out) {
    int b = blockIdx.x, lane = threadIdx.x;
    float s = 0.0f;
    for (int j = lane; j < 3 * Dd; j += 64)
        s += fmaxf(pools[b * (3 * Dd) + j], 0.0f) * W_mlp[j];
    #pragma unroll
    for (int off = 32; off > 0; off >>= 1) s += __shfl_xor(s, off);
    if (lane == 0) out[b] = s + b_mlp[0];
}

extern "C" void kernel_launch(void* const* d_in, const int* in_sizes, int n_in,
                              void* d_out, int out_size, void* d_ws, size_t ws_size,
                              hipStream_t stream) {
    const int*   node_ids = (const int*)d_in[0];
    const int*   src      = (const int*)d_in[1];
    const int*   dst      = (const int*)d_in[2];
    const float* emb      = (const float*)d_in[3];
    const float* W_src    = (const float*)d_in[4];
    const float* b_src    = (const float*)d_in[5];
    const float* W_dst    = (const float*)d_in[6];
    const float* b_dst    = (const float*)d_in[7];
    const float* attn     = (const float*)d_in[8];
    const float* W_res    = (const float*)d_in[9];
    const float* b_res    = (const float*)d_in[10];
    const float* W_gc     = (const float*)d_in[11];
    const float* b_gc     = (const float*)d_in[12];
    const float* W_mlp    = (const float*)d_in[13];
    const float* b_mlp    = (const float*)d_in[14];
    float* out = (float*)d_out;

    char* w = (char*)d_ws;
    size_t off = 0;
    ushort_t* feat_bf = (ushort_t*)(w + off); off += (size_t)(Nn + 64) * Dd * 2;  // 12.8 MB (+pad)
    ushort_t* hs_buf  = (ushort_t*)(w + off); off += (size_t)Nn * HDd * 2;        // 51.2 MB
    ushort_t* hdres   = (ushort_t*)(w + off); off += (size_t)Nn * 1024 * 2;       // 102.4 MB
    ushort_t* Wt      = (ushort_t*)(w + off); off += (size_t)WNf * 128 * 2;
    ushort_t* Wt_gc   = (ushort_t*)(w + off); off += (size_t)128 * 128 * 2;
    float*    bias_f  = (float*)(w + off);    off += (size_t)WNf * 4;
    int*      csr_src = (int*)(w + off);      off += (size_t)Ee * 4;
    int*      row_st  = (int*)(w + off);      off += ((size_t)Nn + 4) * 4;
    // cursor | din_i | dout_f contiguous: single memset zeroes all three
    int*      cursor  = (int*)(w + off);      off += (size_t)Nn * 4;
    int*      din_i   = (int*)(w + off);      off += (size_t)Nn * 4;
    float*    dout_f  = (float*)(w + off);    off += (size_t)Nn * 4;
    float*    din_f   = (float*)(w + off);    off += (size_t)Nn * 4;
    int*      partials= (int*)(w + off);      off += 64 * 4;
    float*    pools   = (float*)(w + off);    off += (size_t)Bg * 3 * Dd * 4;
    ushort_t* res_bf  = (ushort_t*)(w + off); off += (size_t)Nn * Dd * 2;         // 12.8 MB

    ushort_t* agg_bf = hs_buf;                                // hs dead after gat_fused

    hipMemsetAsync(cursor, 0, (size_t)3 * Nn * 4, stream);    // cursor + din_i + dout_f

    setup_kernel<<<(Nn * 32) / 256, 256, 0, stream>>>(
        node_ids, emb, feat_bf, src, dst, W_src, W_dst, W_res, W_gc,
        b_src, b_dst, b_res, Wt, Wt_gc, bias_f,
        din_i, dout_f, pools);
    maxpool_bf_kernel<<<dim3(Bg, 50), 64, 0, stream>>>(feat_bf, pools, 0);

    // CSR build (degrees already accumulated in setup)
    scan_reduce_kernel<<<NCHUNK, 256, 0, stream>>>(din_i, partials);
    scan_mid_kernel<<<1, 64, 0, stream>>>(partials, row_st);
    scan_final_kernel<<<NCHUNK, 256, 0, stream>>>(din_i, partials, row_st, din_f);
    scatter_kernel<<<(Ee + 255) / 256, 256, 0, stream>>>(src, dst, row_st, cursor, csr_src);

    // merged hs|hd|rres GEMM: grid 6256 = 782 rows x 8 col-splits, GNT=3
    mfma_gemm_kernel<<<((Nn + 63) / 64) * NCS, 256, 0, stream>>>(
        feat_bf, Wt, bias_f, hs_buf, hdres, Nn);

    gat_fused_kernel<<<(Nn * 64) / 256, 256, 0, stream>>>(
        hs_buf, hdres, attn, row_st, csr_src, res_bf);
    maxpool_bf_kernel<<<dim3(Bg, 50), 64, 0, stream>>>(res_bf, pools, Dd);

    gc_gather_kernel<<<(Nn * 64) / 256, 256, 0, stream>>>(res_bf, row_st, csr_src, dout_f, din_f, agg_bf);
    mfma_gc_pool_kernel<<<Bg * 98, 256, 0, stream>>>(agg_bf, Wt_gc, b_gc, pools);

    final_kernel<<<Bg, 64, 0, stream>>>(pools, W_mlp, b_mlp, out);
}